// Round 10
// baseline (188.208 us; speedup 1.0000x reference)
//
#include <hip/hip_runtime.h>
#include <math.h>

typedef __attribute__((ext_vector_type(8)))  short short8;   // 8 x bf16 (4 VGPRs)
typedef __attribute__((ext_vector_type(4)))  float f32x4;    // 16x16 MFMA acc
typedef __attribute__((ext_vector_type(16))) float f32x16;   // 32x32 MFMA acc

constexpr int B  = 8;
constexpr int N  = 1024;
constexpr int D  = 512;
constexpr int H  = 8;
constexpr int DH = 64;
constexpr int M_ROWS = 8192;
constexpr float EPS_DIST = 1e-8f;
constexpr float EPS_LN   = 1e-5f;

// fp32 -> bf16 bits (RNE)
__device__ inline unsigned short bfbits(float f) {
    union { float f; unsigned u; } v; v.f = f;
    unsigned r = v.u + 0x7fffu + ((v.u >> 16) & 1u);
    return (unsigned short)(r >> 16);
}
__device__ inline float bf2f(unsigned short s) {
    union { unsigned u; float f; } v; v.u = ((unsigned)s) << 16; return v.f;
}

// async 16B global->LDS (per lane; LDS dest = wave-uniform base + lane*16)
__device__ inline void async_ld16(unsigned short* lds, const unsigned short* g) {
    __builtin_amdgcn_global_load_lds(
        (const __attribute__((address_space(1))) unsigned int*)(g),
        (__attribute__((address_space(3))) unsigned int*)(lds),
        16, 0, 0);
}

__device__ inline float block_sum256(float s, float* red) {
    for (int o = 32; o > 0; o >>= 1) s += __shfl_down(s, o, 64);
    int lane = threadIdx.x & 63, wid = threadIdx.x >> 6;
    if (lane == 0) red[wid] = s;
    __syncthreads();
    if (threadIdx.x == 0) red[4] = red[0] + red[1] + red[2] + red[3];
    __syncthreads();
    return red[4];
}

// ---------------------------------------------------------------------------
// Fused: blocks 0..255 transpose+convert the 4 weights to bf16;
// blocks 256..8447 do LN1 (x -> h bf16).
// ---------------------------------------------------------------------------
__global__ __launch_bounds__(256) void prep_kernel(const float* __restrict__ Wq,
                                                   const float* __restrict__ Wk,
                                                   const float* __restrict__ Wv,
                                                   const float* __restrict__ Wo,
                                                   unsigned short* __restrict__ WtAll,
                                                   const float* __restrict__ x,
                                                   const float* __restrict__ ln1_g,
                                                   const float* __restrict__ ln1_b,
                                                   unsigned short* __restrict__ h_bf) {
    __shared__ float red[8];
    const int bxg = blockIdx.x;
    if (bxg < 256) {
        int sub = bxg >> 6;
        const float* W = sub == 0 ? Wq : sub == 1 ? Wk : sub == 2 ? Wv : Wo;
        unsigned short* Wt = WtAll + (size_t)sub * 262144;
        int t = (bxg & 63) * 256 + threadIdx.x;
        int tn = t & 127, tk = t >> 7;
        int k = tk * 4, n = tn * 4;
        float4 r0 = *(const float4*)&W[(size_t)(k + 0) * 512 + n];
        float4 r1 = *(const float4*)&W[(size_t)(k + 1) * 512 + n];
        float4 r2 = *(const float4*)&W[(size_t)(k + 2) * 512 + n];
        float4 r3 = *(const float4*)&W[(size_t)(k + 3) * 512 + n];
        ushort4 c;
        c.x = bfbits(r0.x); c.y = bfbits(r1.x); c.z = bfbits(r2.x); c.w = bfbits(r3.x);
        *(ushort4*)&Wt[(size_t)(n + 0) * 512 + k] = c;
        c.x = bfbits(r0.y); c.y = bfbits(r1.y); c.z = bfbits(r2.y); c.w = bfbits(r3.y);
        *(ushort4*)&Wt[(size_t)(n + 1) * 512 + k] = c;
        c.x = bfbits(r0.z); c.y = bfbits(r1.z); c.z = bfbits(r2.z); c.w = bfbits(r3.z);
        *(ushort4*)&Wt[(size_t)(n + 2) * 512 + k] = c;
        c.x = bfbits(r0.w); c.y = bfbits(r1.w); c.z = bfbits(r2.w); c.w = bfbits(r3.w);
        *(ushort4*)&Wt[(size_t)(n + 3) * 512 + k] = c;
    } else {
        const int row = bxg - 256;
        const int t = threadIdx.x;
        const float* xr = x + (size_t)row * D;
        float v0 = xr[t], v1 = xr[t + 256];
        float mu = block_sum256(v0 + v1, red) * (1.0f / D);
        float d0 = v0 - mu, d1 = v1 - mu;
        float var = block_sum256(d0 * d0 + d1 * d1, red) * (1.0f / D);
        float rstd = rsqrtf(var + EPS_LN);
        h_bf[(size_t)row * D + t]       = bfbits(d0 * rstd * ln1_g[t] + ln1_b[t]);
        h_bf[(size_t)row * D + t + 256] = bfbits(d1 * rstd * ln1_g[t + 256] + ln1_b[t + 256]);
    }
}

// ---------------------------------------------------------------------------
// LN2: y = LN(bf16 Y0 + fp32 x) -> fp32 out
// ---------------------------------------------------------------------------
__global__ __launch_bounds__(256) void ln2_kernel(const unsigned short* __restrict__ y0,
                                                  const float* __restrict__ res,
                                                  const float* __restrict__ gamma,
                                                  const float* __restrict__ beta,
                                                  float* __restrict__ out) {
    __shared__ float red[8];
    const int row = blockIdx.x;
    const int t = threadIdx.x;
    const unsigned short* xr = y0 + (size_t)row * D;
    const float* rr = res + (size_t)row * D;
    float v0 = bf2f(xr[t]) + rr[t];
    float v1 = bf2f(xr[t + 256]) + rr[t + 256];
    float mu = block_sum256(v0 + v1, red) * (1.0f / D);
    float d0 = v0 - mu, d1 = v1 - mu;
    float var = block_sum256(d0 * d0 + d1 * d1, red) * (1.0f / D);
    float rstd = rsqrtf(var + EPS_LN);
    out[(size_t)row * D + t]       = d0 * rstd * gamma[t] + beta[t];
    out[(size_t)row * D + t + 256] = d1 * rstd * gamma[t + 256] + beta[t + 256];
}

// ---------------------------------------------------------------------------
// 128x128-tile bf16 MFMA GEMM, BK=64, fused QKV epilogue (N=1536):
// Q,K -> [bh][n][dh] + sumsq (coalesced via LDS transpose region),
// V -> [bh][dh][n] via LDS transpose. 1D grid, by = id & 63.
// ---------------------------------------------------------------------------
template <int MT>
__global__ __launch_bounds__(256) void gemm_qkv(const unsigned short* __restrict__ A,
                                                const unsigned short* __restrict__ Wt,
                                                const float* __restrict__ bias0,
                                                const float* __restrict__ bias1,
                                                const float* __restrict__ bias2,
                                                unsigned short* __restrict__ Qo,
                                                unsigned short* __restrict__ Ko,
                                                unsigned short* __restrict__ Vo,
                                                float* __restrict__ sq0,
                                                float* __restrict__ sq1) {
    constexpr int RB = M_ROWS / MT;
    constexpr int NI = MT / 32;
    constexpr int ASZ = MT * 64, BSZ = 128 * 64;
    constexpr int SMSZ = (ASZ + BSZ > 18432) ? ASZ + BSZ : 18432;
    __shared__ unsigned short smem[SMSZ];
    unsigned short* As = smem;
    unsigned short* Bs = smem + ASZ;

    const int id = blockIdx.x;
    const int by = id & (RB - 1), bx = id / RB;
    const int tid = threadIdx.x;
    const int lane = tid & 63, wv = tid >> 6;
    const int quad = lane >> 4, l15 = lane & 15;
    const int row0 = by * MT, col0 = bx * 128;
    const int wm = (wv & 1) * (MT / 2), wn = (wv >> 1) * 64;

    f32x4 acc[NI][4];
    #pragma unroll
    for (int i = 0; i < NI; ++i)
        #pragma unroll
        for (int j = 0; j < 4; ++j) acc[i][j] = (f32x4){0.f, 0.f, 0.f, 0.f};

    const unsigned short* Ag = A  + (size_t)row0 * 512;
    const unsigned short* Bg = Wt + (size_t)col0 * 512;

    for (int k0 = 0; k0 < 512; k0 += 64) {
        __syncthreads();
        #pragma unroll
        for (int c = 0; c < ASZ / 2048; ++c) {
            int fu = c * 2048 + tid * 8;
            int r = fu >> 6, ko = fu & 63;
            async_ld16(As + fu, Ag + (size_t)r * 512 + k0 + ko);
        }
        #pragma unroll
        for (int c = 0; c < BSZ / 2048; ++c) {
            int fu = c * 2048 + tid * 8;
            int r = fu >> 6, ko = fu & 63;
            async_ld16(Bs + fu, Bg + (size_t)r * 512 + k0 + ko);
        }
        __syncthreads();

        #pragma unroll
        for (int ks = 0; ks < 2; ++ks) {
            short8 af[NI], bf[4];
            #pragma unroll
            for (int i = 0; i < NI; ++i)
                af[i] = *(const short8*)&As[(wm + i * 16 + l15) * 64 + ks * 32 + quad * 8];
            #pragma unroll
            for (int j = 0; j < 4; ++j)
                bf[j] = *(const short8*)&Bs[(wn + j * 16 + l15) * 64 + ks * 32 + quad * 8];
            #pragma unroll
            for (int i = 0; i < NI; ++i)
                #pragma unroll
                for (int j = 0; j < 4; ++j)
                    acc[i][j] = __builtin_amdgcn_mfma_f32_16x16x32_bf16(af[i], bf[j], acc[i][j], 0, 0, 0);
        }
    }

    const int colg = col0 + wn;
    const int seg = colg >> 9;                 // 0=Q 1=K 2=V  (block-uniform)
    const int hh = (colg & 511) >> 6;
    const float* bias = seg == 0 ? bias0 : seg == 1 ? bias1 : bias2;

    __syncthreads();                           // done with As/Bs; reuse smem
    unsigned short* T = smem + wv * 4608;      // per-wave [64][72]
    const int b_ = (row0 + wm) >> 10;
    const int nbase = (row0 + wm) & 1023;

    if (seg < 2) {
        unsigned short* dst = seg == 0 ? Qo : Ko;
        float* sq = seg == 0 ? sq0 : sq1;
        #pragma unroll
        for (int i = 0; i < NI; ++i) {
            const int m0 = row0 + wm + i * 16 + quad * 4;
            float ss[4] = {0.f, 0.f, 0.f, 0.f};
            #pragma unroll
            for (int j = 0; j < 4; ++j) {
                float bvj = bias[hh * 64 + j * 16 + l15];
                #pragma unroll
                for (int r = 0; r < 4; ++r) {
                    float v = acc[i][j][r] + bvj;
                    unsigned short ub = bfbits(v);
                    float vr = bf2f(ub);
                    ss[r] += vr * vr;
                    T[(i * 16 + quad * 4 + r) * 72 + j * 16 + l15] = ub;
                }
            }
            #pragma unroll
            for (int r = 0; r < 4; ++r) {
                float s = ss[r];
                s += __shfl_xor(s, 1, 64);
                s += __shfl_xor(s, 2, 64);
                s += __shfl_xor(s, 4, 64);
                s += __shfl_xor(s, 8, 64);
                if (l15 == 0) {
                    int m = m0 + r;
                    sq[(size_t)((m >> 10) * 8 + hh) * 1024 + (m & 1023)] = s;
                }
            }
        }
        // coalesced store: [bh][n][dh], 8 consecutive n-rows (128B each) per instr
        unsigned short* dg = dst + ((size_t)((b_ * 8 + hh) * 1024) + nbase) * 64;
        #pragma unroll
        for (int it = 0; it < 8; ++it) {
            int rr2 = it * 8 + (lane >> 3);
            int cc2 = (lane & 7) * 8;
            *(uint4*)&dg[(size_t)rr2 * 64 + cc2] = *(const uint4*)&T[rr2 * 72 + cc2];
        }
    } else {
        // V: transpose through per-wave LDS region, then coalesced stores
        #pragma unroll
        for (int i = 0; i < NI; ++i)
            #pragma unroll
            for (int j = 0; j < 4; ++j) {
                float bvj = bias[hh * 64 + j * 16 + l15];
                ushort4 pk;
                pk.x = bfbits(acc[i][j][0] + bvj);
                pk.y = bfbits(acc[i][j][1] + bvj);
                pk.z = bfbits(acc[i][j][2] + bvj);
                pk.w = bfbits(acc[i][j][3] + bvj);
                *(ushort4*)&T[(j * 16 + l15) * 72 + i * 16 + quad * 4] = pk;
            }
        unsigned short* Vg = Vo + ((size_t)((b_ * 8 + hh) * 64)) * 1024 + nbase;
        #pragma unroll
        for (int it = 0; it < 8; ++it) {
            int dl = it * 8 + (lane >> 3);
            int nl = (lane & 7) * 8;
            uint4 v = *(const uint4*)&T[dl * 72 + nl];
            *(uint4*)&Vg[(size_t)dl * 1024 + nl] = v;
        }
    }
}

// ---------------------------------------------------------------------------
// Out-projection GEMM: Ob[M,512] @ WtO -> Y0 bf16. 64x128 tile, BK=64,
// coalesced epilogue via LDS. 512 blocks, by = id & 127.
// ---------------------------------------------------------------------------
__global__ __launch_bounds__(256) void gemm_out(const unsigned short* __restrict__ A,
                                                const unsigned short* __restrict__ Wt,
                                                const float* __restrict__ bias,
                                                unsigned short* __restrict__ C) {
    __shared__ unsigned short smem[64 * 64 + 128 * 64];
    unsigned short* As = smem;
    unsigned short* Bs = smem + 64 * 64;

    const int id = blockIdx.x;
    const int by = id & 127, bx = id >> 7;
    const int tid = threadIdx.x;
    const int lane = tid & 63, wv = tid >> 6;
    const int quad = lane >> 4, l15 = lane & 15;
    const int row0 = by * 64, col0 = bx * 128;
    const int wm = (wv & 1) * 32, wn = (wv >> 1) * 64;

    f32x4 acc[2][4];
    #pragma unroll
    for (int i = 0; i < 2; ++i)
        #pragma unroll
        for (int j = 0; j < 4; ++j) acc[i][j] = (f32x4){0.f, 0.f, 0.f, 0.f};

    const unsigned short* Ag = A  + (size_t)row0 * 512;
    const unsigned short* Bg = Wt + (size_t)col0 * 512;

    for (int k0 = 0; k0 < 512; k0 += 64) {
        __syncthreads();
        #pragma unroll
        for (int c = 0; c < 2; ++c) {
            int fu = c * 2048 + tid * 8;
            int r = fu >> 6, ko = fu & 63;
            async_ld16(As + fu, Ag + (size_t)r * 512 + k0 + ko);
        }
        #pragma unroll
        for (int c = 0; c < 4; ++c) {
            int fu = c * 2048 + tid * 8;
            int r = fu >> 6, ko = fu & 63;
            async_ld16(Bs + fu, Bg + (size_t)r * 512 + k0 + ko);
        }
        __syncthreads();

        #pragma unroll
        for (int ks = 0; ks < 2; ++ks) {
            short8 af[2], bf[4];
            #pragma unroll
            for (int i = 0; i < 2; ++i)
                af[i] = *(const short8*)&As[(wm + i * 16 + l15) * 64 + ks * 32 + quad * 8];
            #pragma unroll
            for (int j = 0; j < 4; ++j)
                bf[j] = *(const short8*)&Bs[(wn + j * 16 + l15) * 64 + ks * 32 + quad * 8];
            #pragma unroll
            for (int i = 0; i < 2; ++i)
                #pragma unroll
                for (int j = 0; j < 4; ++j)
                    acc[i][j] = __builtin_amdgcn_mfma_f32_16x16x32_bf16(af[i], bf[j], acc[i][j], 0, 0, 0);
        }
    }

    __syncthreads();
    unsigned short* T = smem + wv * 2304;      // per-wave [32][72]
    #pragma unroll
    for (int i = 0; i < 2; ++i)
        #pragma unroll
        for (int j = 0; j < 4; ++j) {
            float bv = bias[col0 + wn + j * 16 + l15];
            #pragma unroll
            for (int r = 0; r < 4; ++r)
                T[(i * 16 + quad * 4 + r) * 72 + j * 16 + l15] = bfbits(acc[i][j][r] + bv);
        }
    #pragma unroll
    for (int it = 0; it < 4; ++it) {
        int rr2 = it * 8 + (lane >> 3);
        int cc2 = (lane & 7) * 8;
        *(uint4*)&C[(size_t)(row0 + wm + rr2) * 512 + col0 + wn + cc2] =
            *(const uint4*)&T[rr2 * 72 + cc2];
    }
}

// ---------------------------------------------------------------------------
// MFMA distance attention, 32x32x16, fragment-order LDS (conflict-free,
// immediate-offset ds ops). Block = 4 waves (256 thr), 32 q/wave = 128 q per
// (b,h). S^T = K.Q^T (C cols = q -> per-lane denominator); P packed as b64.
// LDS layouts:
//   K/V tile (64 rows x 64 k): off(row,k) = (k>>3)*512 + row*8 + (k&7)
//   P tile   (32 q  x 64 key): off(q,key) = (key>>3)*256 + q*8 + (key&7)
// Fragment read (A/B-op, lane l31/half, chunk ks): base + lane*8 -> lane-linear.
// bh = id & 63 (XCD-local).
// ---------------------------------------------------------------------------
__global__ __launch_bounds__(256) void attn_kernel(const unsigned short* __restrict__ Q,
                                                   const unsigned short* __restrict__ K,
                                                   const unsigned short* __restrict__ Vt,
                                                   const float* __restrict__ qsq,
                                                   const float* __restrict__ ksq,
                                                   unsigned short* __restrict__ O) {
    __shared__ unsigned short Ks[4096];        // fragment-order K tile
    __shared__ unsigned short Vs[4096];        // fragment-order V^T tile
    __shared__ unsigned short Ps[4][2048];     // per-wave fragment-order P
    __shared__ float ksq_s[64];
    __shared__ float dinv_s[4][32];

    const int id = blockIdx.x;
    const int bh = id & 63, qb = id >> 6;      // qb 0..7
    const int q0 = qb * 128;
    const int tid = threadIdx.x;
    const int lane = tid & 63, w = tid >> 6;
    const int half = lane >> 5, l31 = lane & 31;
    const int b_ = bh >> 3, h_ = bh & 7;

    const unsigned short* Qb = Q  + (size_t)bh * N * DH;
    const unsigned short* Kb = K  + (size_t)bh * N * DH;
    const unsigned short* Vb = Vt + (size_t)bh * DH * N;

    const int qrow = q0 + w * 32 + l31;

    // Q fragments in registers: B-operand [n=q][k=d]
    short8 qa[4];
    {
        const unsigned short* qp = Qb + (size_t)qrow * 64 + half * 8;
        #pragma unroll
        for (int ks = 0; ks < 4; ++ks) qa[ks] = *(const short8*)(qp + ks * 16);
    }
    const float qeps = qsq[bh * N + qrow] + EPS_DIST;

    f32x16 oacc[2];
    #pragma unroll
    for (int dt = 0; dt < 2; ++dt)
        #pragma unroll
        for (int r = 0; r < 16; ++r) oacc[dt][r] = 0.f;
    float dpart = 0.f;

    // staging: thread (rr, cc) loads row rr, k-cols cc..cc+15 (2 x 16B)
    const int rr = tid >> 2, cc = (tid & 3) * 16;
    const int g0 = (cc >> 3) * 512 + rr * 8;   // fragment-order dest of 1st 16B
    uint4 kreg0, kreg1, vreg0, vreg1;
    float ksreg = 0.f;

    kreg0 = *(const uint4*)(Kb + (size_t)rr * 64 + cc);
    kreg1 = *(const uint4*)(Kb + (size_t)rr * 64 + cc + 8);
    vreg0 = *(const uint4*)(Vb + (size_t)rr * N + cc);
    vreg1 = *(const uint4*)(Vb + (size_t)rr * N + cc + 8);
    if (tid < 64) ksreg = ksq[bh * N + tid];

    *(uint4*)&Ks[g0]       = kreg0;
    *(uint4*)&Ks[g0 + 512] = kreg1;
    *(uint4*)&Vs[g0]       = vreg0;
    *(uint4*)&Vs[g0 + 512] = vreg1;
    if (tid < 64) ksq_s[tid] = ksreg;
    __syncthreads();

    for (int kt = 0; kt < 16; ++kt) {
        if (kt < 15) {   // prefetch next tile into registers
            kreg0 = *(const uint4*)(Kb + (size_t)((kt + 1) * 64 + rr) * 64 + cc);
            kreg1 = *(const uint4*)(Kb + (size_t)((kt + 1) * 64 + rr) * 64 + cc + 8);
            vreg0 = *(const uint4*)(Vb + (size_t)rr * N + (kt + 1) * 64 + cc);
            vreg1 = *(const uint4*)(Vb + (size_t)rr * N + (kt + 1) * 64 + cc + 8);
            if (tid < 64) ksreg = ksq[bh * N + (kt + 1) * 64 + tid];
        }

        // S^T = K.Q^T: A = K-frag [m=key][k=d], B = Q-frag (registers)
        f32x16 sacc[2];
        #pragma unroll
        for (int kb = 0; kb < 2; ++kb)
            #pragma unroll
            for (int r = 0; r < 16; ++r) sacc[kb][r] = 0.f;
        #pragma unroll
        for (int ks = 0; ks < 4; ++ks) {
            const int fb = (ks * 2 + half) * 512;
            short8 kf0 = *(const short8*)&Ks[fb + l31 * 8];
            short8 kf1 = *(const short8*)&Ks[fb + (32 + l31) * 8];
            sacc[0] = __builtin_amdgcn_mfma_f32_32x32x16_bf16(kf0, qa[ks], sacc[0], 0, 0, 0);
            sacc[1] = __builtin_amdgcn_mfma_f32_32x32x16_bf16(kf1, qa[ks], sacc[1], 0, 0, 0);
        }

        // transform: C col = q (= l31), row = key = (r&3) + 8*(r>>2) + 4*half
        #pragma unroll
        for (int kb = 0; kb < 2; ++kb) {
            #pragma unroll
            for (int g = 0; g < 4; ++g) {
                const int keyl = kb * 32 + 8 * g + 4 * half;
                float4 ks2v = *(const float4*)&ksq_s[keyl];
                union { float f; unsigned u; } p0, p1, p2, p3;
                {
                    float d2 = fmaf(-2.0f, sacc[kb][4 * g + 0], qeps + ks2v.x);
                    p0.f = __expf(-__builtin_amdgcn_sqrtf(fmaxf(d2, EPS_DIST)));
                    d2 = fmaf(-2.0f, sacc[kb][4 * g + 1], qeps + ks2v.y);
                    p1.f = __expf(-__builtin_amdgcn_sqrtf(fmaxf(d2, EPS_DIST)));
                    d2 = fmaf(-2.0f, sacc[kb][4 * g + 2], qeps + ks2v.z);
                    p2.f = __expf(-__builtin_amdgcn_sqrtf(fmaxf(d2, EPS_DIST)));
                    d2 = fmaf(-2.0f, sacc[kb][4 * g + 3], qeps + ks2v.w);
                    p3.f = __expf(-__builtin_amdgcn_sqrtf(fmaxf(d2, EPS_DIST)));
                }
                dpart += (p0.f + p1.f) + (p2.f + p3.f);
                uint2 pk;
                pk.x = __builtin_amdgcn_perm(p1.u, p0.u, 0x07060302);
                pk.y = __builtin_amdgcn_perm(p3.u, p2.u, 0x07060302);
                // fragment-order: off = (key>>3)*256 + q*8 + (key&7); key&7 = 4*half
                *(uint2*)&Ps[w][(kb * 4 + g) * 256 + l31 * 8 + 4 * half] = pk;
            }
        }

        // PV: O[q][d] = P[q][key] . V^T[d][key];  A = P-frag, B = V-frag
        #pragma unroll
        for (int ks = 0; ks < 4; ++ks) {
            const int pb = (ks * 2 + half) * 256;
            const int fb = (ks * 2 + half) * 512;
            short8 pa  = *(const short8*)&Ps[w][pb + l31 * 8];
            short8 vf0 = *(const short8*)&Vs[fb + l31 * 8];
            short8 vf1 = *(const short8*)&Vs[fb + (32 + l31) * 8];
            oacc[0] = __builtin_amdgcn_mfma_f32_32x32x16_bf16(pa, vf0, oacc[0], 0, 0, 0);
            oacc[1] = __builtin_amdgcn_mfma_f32_32x32x16_bf16(pa, vf1, oacc[1], 0, 0, 0);
        }

        if (kt < 15) {
            __syncthreads();   // all waves done reading tile kt
            *(uint4*)&Ks[g0]       = kreg0;
            *(uint4*)&Ks[g0 + 512] = kreg1;
            *(uint4*)&Vs[g0]       = vreg0;
            *(uint4*)&Vs[g0 + 512] = vreg1;
            if (tid < 64) ksq_s[tid] = ksreg;
            __syncthreads();   // writes visible
        }
    }

    // denominator: lane pair (l31, l31+32) covers same q, disjoint keys
    dpart += __shfl_xor(dpart, 32, 64);
    if (half == 0) dinv_s[w][l31] = 1.0f / dpart;

    // O write: col = d = dt*32 + l31, row q = (r&3) + 8*(r>>2) + 4*half
    #pragma unroll
    for (int r = 0; r < 16; ++r) {
        const int lq = (r & 3) + 8 * (r >> 2) + 4 * half;
        const float rinv = dinv_s[w][lq];
        const int n_ = q0 + w * 32 + lq;
        unsigned short* og = O + ((size_t)(b_ * N + n_) * D) + h_ * DH;
        og[l31]      = bfbits(oacc[0][r] * rinv);
        og[32 + l31] = bfbits(oacc[1][r] * rinv);
    }
}

// ---------------------------------------------------------------------------
extern "C" void kernel_launch(void* const* d_in, const int* in_sizes, int n_in,
                              void* d_out, int out_size, void* d_ws, size_t ws_size,
                              hipStream_t stream) {
    const float* x     = (const float*)d_in[0];
    const float* Wq    = (const float*)d_in[1];
    const float* Wk    = (const float*)d_in[2];
    const float* Wv    = (const float*)d_in[3];
    const float* Wo    = (const float*)d_in[4];
    const float* bq    = (const float*)d_in[5];
    const float* bk    = (const float*)d_in[6];
    const float* bv    = (const float*)d_in[7];
    const float* bo    = (const float*)d_in[8];
    const float* ln1_g = (const float*)d_in[9];
    const float* ln1_b = (const float*)d_in[10];
    const float* ln2_g = (const float*)d_in[11];
    const float* ln2_b = (const float*)d_in[12];
    float* out = (float*)d_out;

    unsigned short* WtAll = (unsigned short*)d_ws;    // [4][512][512] bf16
    unsigned short* h_bf  = WtAll + 4 * 262144;       // [8192][512]
    unsigned short* Qb    = h_bf + 4194304;           // [64][1024][64]
    unsigned short* Kb    = Qb + 4194304;
    unsigned short* Vtg   = Kb + 4194304;             // [64][64][1024] transposed
    unsigned short* Ob    = Vtg + 4194304;            // [8192][512]
    unsigned short* Y0    = Ob + 4194304;             // [8192][512] bf16
    float* qsq = (float*)(Y0 + 4194304);              // [65536]
    float* ksq = qsq + 65536;

    // 1) weights -> bf16^T  +  LN1 -> bf16 (fused launch)
    prep_kernel<<<256 + M_ROWS, 256, 0, stream>>>(Wq, Wk, Wv, Wo, WtAll,
                                                  x, ln1_g, ln1_b, h_bf);

    // 2) fused QKV projection (N=1536) + scatter + sum-squares
    gemm_qkv<128><<<768, 256, 0, stream>>>(h_bf, WtAll, bq, bk, bv,
                                           Qb, Kb, Vtg, qsq, ksq);

    // 3) MFMA distance attention -> Ob [B,N,D] bf16 (512 blocks, 32x32 MFMA)
    attn_kernel<<<512, 256, 0, stream>>>(Qb, Kb, Vtg, qsq, ksq, Ob);

    // 4) output projection -> bf16 Y0
    gemm_out<<<512, 256, 0, stream>>>(Ob, WtAll + 3 * 262144, bo, Y0);

    // 5) residual + post-norm
    ln2_kernel<<<M_ROWS, 256, 0, stream>>>(Y0, x, ln2_g, ln2_b, out);
}